// Round 2
// baseline (1474.615 us; speedup 1.0000x reference)
//
#include <hip/hip_runtime.h>

#define NN    131072
#define NPL   16384
#define LVLS  8
#define DEG   16
#define DIM   128
#define HID   64
#define NODES 64            // dst nodes per block
#define WAVES 8             // waves per block (512 threads)
#define NPW   (NODES/WAVES) // nodes gathered per wave

// transposed-weight float offsets inside d_ws
#define AW1T 0
#define AW2T 8192
#define AW3T 12288
#define IW1T 20480
#define IW2T 28672
#define IW3T 32768
#define INVBUF_OFF 65536    // floats (256KB in)

__device__ __forceinline__ float lrelu(float x) { return x >= 0.f ? x : 0.01f * x; }

// dword offset of x[node][i] in the quad-XOR-swizzled [64][128] layout.
// Quad q of node n lives at quad (q ^ n) & 31 -> ds_read_b128 of a node's
// row is bank-conflict-free across lanes (lane = node), and the gather's
// float2 writes (node uniform, lanes = elem pairs) are conflict-free too.
__device__ __forceinline__ int xsw(int node, int i) {
    return node * DIM + ((((i >> 2) ^ node) & 31) << 2) + (i & 3);
}

// One linear layer for this wave's slice of output columns.
// xin: per-lane input activations in registers (lane = node).
// wT [NOUT][NIN] transposed weights (wave-uniform -> s_load), b bias.
// OUT_SW: write via xsw (layer 3, [node][128] buffer) else plain [j][64].
template<int NIN, int JS, bool ACT, bool OUT_SW>
__device__ __forceinline__ void layer(const float* __restrict__ wT,
                                      const float* __restrict__ b,
                                      int j0, int lane,
                                      const float* __restrict__ xin,
                                      float* __restrict__ outL)
{
#pragma unroll 2
    for (int jj = 0; jj < JS; ++jj) {
        int j = j0 + jj;                      // wave-uniform
        const float* wc = wT + j * NIN;       // uniform -> scalar loads
        float a0 = 0.f, a1 = 0.f, a2 = 0.f, a3 = 0.f;
#pragma unroll
        for (int i = 0; i < NIN; i += 4) {
            a0 = fmaf(xin[i + 0], wc[i + 0], a0);
            a1 = fmaf(xin[i + 1], wc[i + 1], a1);
            a2 = fmaf(xin[i + 2], wc[i + 2], a2);
            a3 = fmaf(xin[i + 3], wc[i + 3], a3);
        }
        float r = ((a0 + a1) + (a2 + a3)) + b[j];
        if (ACT) r = lrelu(r);
        if (OUT_SW) outL[xsw(lane, j)] = r;   // 8-way conflict, 128 instrs/block: cheap
        else        outL[j * NODES + lane] = r; // lane-contiguous: conflict-free
    }
}

// 3-layer MLP(D -> H -> H -> D), LeakyReLU after L1/L2. Input and output both
// live in sA as quad-swizzled [node][128] (output may alias input: separated
// by two barriers). y1L/y2L: plain [64][64] scratch.
__device__ __forceinline__ void mlp3(const float* __restrict__ wT1, const float* __restrict__ b1,
                                     const float* __restrict__ wT2, const float* __restrict__ b2,
                                     const float* __restrict__ wT3, const float* __restrict__ b3,
                                     int wv, int lane,
                                     float* __restrict__ sA,
                                     float* __restrict__ y1L, float* __restrict__ y2L)
{
    float x[DIM];
#pragma unroll
    for (int q = 0; q < DIM / 4; ++q) {       // ds_read_b128, conflict-free
        float4 v = *(const float4*)&sA[xsw(lane, q * 4)];
        x[q * 4 + 0] = v.x; x[q * 4 + 1] = v.y;
        x[q * 4 + 2] = v.z; x[q * 4 + 3] = v.w;
    }
    layer<DIM, HID / WAVES, true, false>(wT1, b1, wv * (HID / WAVES), lane, x, y1L);
    __syncthreads();

    float x2[HID];
#pragma unroll
    for (int i = 0; i < HID; i += 2) {        // pairs -> ds_read2_b32
        x2[i]     = y1L[i * NODES + lane];
        x2[i + 1] = y1L[(i + 1) * NODES + lane];
    }
    layer<HID, HID / WAVES, true, false>(wT2, b2, wv * (HID / WAVES), lane, x2, y2L);
    __syncthreads();

    float x3[HID];
#pragma unroll
    for (int i = 0; i < HID; i += 2) {
        x3[i]     = y2L[i * NODES + lane];
        x3[i + 1] = y2L[(i + 1) * NODES + lane];
    }
    layer<HID, DIM / WAVES, false, true>(wT3, b3, wv * (DIM / WAVES), lane, x3, sA);
    __syncthreads();
}

// Write this wave's NPW node rows from sA (swizzled [node][128]) to global,
// coalesced float2 per lane.
__device__ __forceinline__ void write_rows(float* __restrict__ dst,
                                           const float* __restrict__ sA,
                                           int wv, int lane, int rowBase)
{
#pragma unroll
    for (int n = 0; n < NPW; ++n) {
        int ln = wv * NPW + n;
        float2 v = *(const float2*)&sA[xsw(ln, lane * 2)];
        *(float2*)&dst[(size_t)(rowBase + ln) * DIM + lane * 2] = v;
    }
}

template<bool DO_INV>
__global__ __launch_bounds__(512) void agg_kernel(
    float* __restrict__ hbuf, float* __restrict__ invbuf,
    const int* __restrict__ esrc, const int* __restrict__ emask,
    const float* __restrict__ wts,
    const float* __restrict__ ab1, const float* __restrict__ ab2, const float* __restrict__ ab3,
    const float* __restrict__ ib1, const float* __restrict__ ib2, const float* __restrict__ ib3,
    int dstBase)
{
    __shared__ float sA[NODES * DIM];   // xmean, then y3 (aliased) — 32KB
    __shared__ float y1L[HID * NODES];  // 16KB
    __shared__ float y2L[HID * NODES];  // 16KB  (total exactly 64KB)

    int lane = threadIdx.x & 63;
    int wv   = __builtin_amdgcn_readfirstlane((int)(threadIdx.x >> 6));
    int blockNode0 = blockIdx.x * NODES;

    // ---- gather + masked select + mean: wave w stages nodes [w*8, w*8+8)
#pragma unroll
    for (int n = 0; n < NPW; ++n) {
        int node = blockNode0 + wv * NPW + n;          // level-local dst index
        const int* ep = esrc  + node * DEG;            // uniform -> s_load x16
        const int* mp = emask + node * DEG;
        float ax = 0.f, ay = 0.f;
#pragma unroll
        for (int e = 0; e < DEG; ++e) {
            int s = ep[e];
            int m = mp[e];
            const float* p = m ? invbuf : hbuf;        // uniform s_cselect
            float2 v = *(const float2*)&p[(size_t)s * DIM + lane * 2];
            ax += v.x; ay += v.y;
        }
        int ln = wv * NPW + n;
        *(float2*)&sA[xsw(ln, lane * 2)] = make_float2(ax * 0.0625f, ay * 0.0625f);
    }
    __syncthreads();

    // ---- and-MLP: sA(xmean) -> sA(y3 = new h)
    mlp3(wts + AW1T, ab1, wts + AW2T, ab2, wts + AW3T, ab3, wv, lane, sA, y1L, y2L);
    write_rows(hbuf, sA, wv, lane, dstBase + blockNode0);

    if (DO_INV) {
        // ---- inv-MLP on the fresh h (still in sA) -> sA, write inv rows
        mlp3(wts + IW1T, ib1, wts + IW2T, ib2, wts + IW3T, ib3, wv, lane, sA, y1L, y2L);
        write_rows(invbuf, sA, wv, lane, dstBase + blockNode0);
    }
}

// inv_h for level 0: stage rows coalesced, run inv-MLP, write invbuf.
__global__ __launch_bounds__(512) void inv0_kernel(
    const float* __restrict__ h0, float* __restrict__ invbuf,
    const float* __restrict__ wts,
    const float* __restrict__ ib1, const float* __restrict__ ib2, const float* __restrict__ ib3)
{
    __shared__ float sA[NODES * DIM];
    __shared__ float y1L[HID * NODES];
    __shared__ float y2L[HID * NODES];

    int lane = threadIdx.x & 63;
    int wv   = __builtin_amdgcn_readfirstlane((int)(threadIdx.x >> 6));
    int blockNode0 = blockIdx.x * NODES;

#pragma unroll
    for (int n = 0; n < NPW; ++n) {
        int ln = wv * NPW + n;
        float2 v = *(const float2*)&h0[(size_t)(blockNode0 + ln) * DIM + lane * 2];
        *(float2*)&sA[xsw(ln, lane * 2)] = v;
    }
    __syncthreads();

    mlp3(wts + IW1T, ib1, wts + IW2T, ib2, wts + IW3T, ib3, wv, lane, sA, y1L, y2L);
    write_rows(invbuf, sA, wv, lane, blockNode0);
}

// Transpose the 6 weight matrices into ws so weight columns are contiguous
// (enables s_load_dwordx16 batches in layer()).
__global__ void prep_kernel(const float* __restrict__ iw1, const float* __restrict__ iw2,
                            const float* __restrict__ iw3, const float* __restrict__ aw1,
                            const float* __restrict__ aw2, const float* __restrict__ aw3,
                            float* __restrict__ wts)
{
    int t = blockIdx.x * blockDim.x + threadIdx.x;
    int stride = gridDim.x * blockDim.x;
    // w1 [DIM][HID] -> w1T [HID][DIM]
    for (int idx = t; idx < DIM * HID; idx += stride) {
        int j = idx / DIM, i = idx % DIM;
        wts[AW1T + idx] = aw1[i * HID + j];
        wts[IW1T + idx] = iw1[i * HID + j];
    }
    // w2 [HID][HID] -> w2T [HID][HID]
    for (int idx = t; idx < HID * HID; idx += stride) {
        int j = idx / HID, i = idx % HID;
        wts[AW2T + idx] = aw2[i * HID + j];
        wts[IW2T + idx] = iw2[i * HID + j];
    }
    // w3 [HID][DIM] -> w3T [DIM][HID]
    for (int idx = t; idx < DIM * HID; idx += stride) {
        int j = idx / HID, i = idx % HID;
        wts[AW3T + idx] = aw3[i * DIM + j];
        wts[IW3T + idx] = iw3[i * DIM + j];
    }
}

extern "C" void kernel_launch(void* const* d_in, const int* in_sizes, int n_in,
                              void* d_out, int out_size, void* d_ws, size_t ws_size,
                              hipStream_t stream)
{
    const float* h     = (const float*)d_in[0];
    const int*   esrc  = (const int*)d_in[1];   // [L-1][NPL][DEG]
    const int*   emask = (const int*)d_in[2];
    const float* iw1 = (const float*)d_in[3];
    const float* ib1 = (const float*)d_in[4];
    const float* iw2 = (const float*)d_in[5];
    const float* ib2 = (const float*)d_in[6];
    const float* iw3 = (const float*)d_in[7];
    const float* ib3 = (const float*)d_in[8];
    const float* aw1 = (const float*)d_in[9];
    const float* ab1 = (const float*)d_in[10];
    const float* aw2 = (const float*)d_in[11];
    const float* ab2 = (const float*)d_in[12];
    const float* aw3 = (const float*)d_in[13];
    const float* ab3 = (const float*)d_in[14];

    float* out    = (float*)d_out;
    float* wts    = (float*)d_ws;
    float* invbuf = wts + INVBUF_OFF;   // inv_h rows for nodes 0..114687 (~59MB)

    prep_kernel<<<40, 256, 0, stream>>>(iw1, iw2, iw3, aw1, aw2, aw3, wts);

    // only level-0 rows pass through; levels 1..7 are fully overwritten
    hipMemcpyAsync(out, h, (size_t)NPL * DIM * sizeof(float),
                   hipMemcpyDeviceToDevice, stream);

    const int grid = NPL / NODES;  // 256 blocks -> 1 per CU

    inv0_kernel<<<grid, 512, 0, stream>>>(h, invbuf, wts, ib1, ib2, ib3);

    for (int lvl = 1; lvl < LVLS; ++lvl) {
        const int* es = esrc  + (size_t)(lvl - 1) * NPL * DEG;
        const int* em = emask + (size_t)(lvl - 1) * NPL * DEG;
        if (lvl < LVLS - 1)
            agg_kernel<true><<<grid, 512, 0, stream>>>(
                out, invbuf, es, em, wts, ab1, ab2, ab3, ib1, ib2, ib3, lvl * NPL);
        else
            agg_kernel<false><<<grid, 512, 0, stream>>>(
                out, invbuf, es, em, wts, ab1, ab2, ab3, ib1, ib2, ib3, lvl * NPL);
    }
}

// Round 3
// 616.399 us; speedup vs baseline: 2.3923x; 2.3923x over previous
//
#include <hip/hip_runtime.h>
#include <hip/hip_fp16.h>

#define NN    131072
#define NPL   16384
#define LVLS  8
#define DEG   16
#define DIM   128
#define HID   64

__device__ __forceinline__ float lrelu(float x) { return x >= 0.f ? x : 0.01f * x; }

// Per-wave: push 4 nodes through MLP(DIM->HID->HID->DIM), LeakyReLU(0.01)
// after layers 1 and 2. Lane j computes output column j (and j+64 in layer 3).
// Activations broadcast from LDS via wide reads (ds_read_b128/b64, conflict-free
// broadcast); weights are lane-coalesced 256B VMEM loads (L1/L2-hit), amortized
// over 4 nodes. Proven structure from round 1 (absmax 2.4e-4, ~30us/kernel).
__device__ __forceinline__ void mlp_wave4(
    const float* __restrict__ pw1, const float* __restrict__ pb1,
    const float* __restrict__ pw2, const float* __restrict__ pb2,
    const float* __restrict__ pw3, const float* __restrict__ pb3,
    float (*__restrict__ xs)[DIM],
    float (*__restrict__ y1s)[HID],
    float (*__restrict__ y2s)[HID],
    int lane, float lo[4], float hi[4])
{
    // ---- layer 1: [4][128] @ [128][64]
    float a0 = pb1[lane], a1 = a0, a2 = a0, a3 = a0;
#pragma unroll
    for (int i = 0; i < DIM; i += 4) {
        float w0 = pw1[(i + 0) * HID + lane];
        float w1 = pw1[(i + 1) * HID + lane];
        float w2 = pw1[(i + 2) * HID + lane];
        float w3 = pw1[(i + 3) * HID + lane];
        float4 x0 = *(const float4*)&xs[0][i];
        float4 x1 = *(const float4*)&xs[1][i];
        float4 x2 = *(const float4*)&xs[2][i];
        float4 x3 = *(const float4*)&xs[3][i];
        a0 = fmaf(x0.w, w3, fmaf(x0.z, w2, fmaf(x0.y, w1, fmaf(x0.x, w0, a0))));
        a1 = fmaf(x1.w, w3, fmaf(x1.z, w2, fmaf(x1.y, w1, fmaf(x1.x, w0, a1))));
        a2 = fmaf(x2.w, w3, fmaf(x2.z, w2, fmaf(x2.y, w1, fmaf(x2.x, w0, a2))));
        a3 = fmaf(x3.w, w3, fmaf(x3.z, w2, fmaf(x3.y, w1, fmaf(x3.x, w0, a3))));
    }
    y1s[0][lane] = lrelu(a0);
    y1s[1][lane] = lrelu(a1);
    y1s[2][lane] = lrelu(a2);
    y1s[3][lane] = lrelu(a3);
    __syncthreads();

    // ---- layer 2: [4][64] @ [64][64]
    float c0 = pb2[lane], c1 = c0, c2 = c0, c3 = c0;
#pragma unroll
    for (int i = 0; i < HID; i += 4) {
        float w0 = pw2[(i + 0) * HID + lane];
        float w1 = pw2[(i + 1) * HID + lane];
        float w2 = pw2[(i + 2) * HID + lane];
        float w3 = pw2[(i + 3) * HID + lane];
        float4 x0 = *(const float4*)&y1s[0][i];
        float4 x1 = *(const float4*)&y1s[1][i];
        float4 x2 = *(const float4*)&y1s[2][i];
        float4 x3 = *(const float4*)&y1s[3][i];
        c0 = fmaf(x0.w, w3, fmaf(x0.z, w2, fmaf(x0.y, w1, fmaf(x0.x, w0, c0))));
        c1 = fmaf(x1.w, w3, fmaf(x1.z, w2, fmaf(x1.y, w1, fmaf(x1.x, w0, c1))));
        c2 = fmaf(x2.w, w3, fmaf(x2.z, w2, fmaf(x2.y, w1, fmaf(x2.x, w0, c2))));
        c3 = fmaf(x3.w, w3, fmaf(x3.z, w2, fmaf(x3.y, w1, fmaf(x3.x, w0, c3))));
    }
    y2s[0][lane] = lrelu(c0);
    y2s[1][lane] = lrelu(c1);
    y2s[2][lane] = lrelu(c2);
    y2s[3][lane] = lrelu(c3);
    __syncthreads();

    // ---- layer 3: [4][64] @ [64][128]; lane -> columns lane and lane+64
    float t0 = pb3[lane], t1 = pb3[64 + lane];
    lo[0] = t0; lo[1] = t0; lo[2] = t0; lo[3] = t0;
    hi[0] = t1; hi[1] = t1; hi[2] = t1; hi[3] = t1;
#pragma unroll
    for (int i = 0; i < HID; i += 2) {
        float wl0 = pw3[(i + 0) * DIM + lane], wh0 = pw3[(i + 0) * DIM + 64 + lane];
        float wl1 = pw3[(i + 1) * DIM + lane], wh1 = pw3[(i + 1) * DIM + 64 + lane];
        float2 s0 = *(const float2*)&y2s[0][i];
        float2 s1 = *(const float2*)&y2s[1][i];
        float2 s2 = *(const float2*)&y2s[2][i];
        float2 s3 = *(const float2*)&y2s[3][i];
        lo[0] = fmaf(s0.y, wl1, fmaf(s0.x, wl0, lo[0])); hi[0] = fmaf(s0.y, wh1, fmaf(s0.x, wh0, hi[0]));
        lo[1] = fmaf(s1.y, wl1, fmaf(s1.x, wl0, lo[1])); hi[1] = fmaf(s1.y, wh1, fmaf(s1.x, wh0, hi[1]));
        lo[2] = fmaf(s2.y, wl1, fmaf(s2.x, wl0, lo[2])); hi[2] = fmaf(s2.y, wh1, fmaf(s2.x, wh0, hi[2]));
        lo[3] = fmaf(s3.y, wl1, fmaf(s3.x, wl0, lo[3])); hi[3] = fmaf(s3.y, wh1, fmaf(s3.x, wh0, hi[3]));
    }
}

// Fused per-level kernel: gather fp16 rows (mask ? inv16 : h16), mean,
// and-MLP -> write fp32 h + fp16 mirror; then (DO_INV) inv-MLP on the fresh h
// -> write fp16 inv mirror. Block = 256 threads / 16 nodes; grid = 1024.
template<bool DO_INV>
__global__ __launch_bounds__(256, 4) void agg_kernel(
    float* __restrict__ hout,
    __half* __restrict__ h16, __half* __restrict__ inv16,
    const int* __restrict__ esrc, const int* __restrict__ emask,
    const float* __restrict__ aw1, const float* __restrict__ ab1,
    const float* __restrict__ aw2, const float* __restrict__ ab2,
    const float* __restrict__ aw3, const float* __restrict__ ab3,
    const float* __restrict__ iw1, const float* __restrict__ ib1,
    const float* __restrict__ iw2, const float* __restrict__ ib2,
    const float* __restrict__ iw3, const float* __restrict__ ib3,
    int dstBase)
{
    __shared__ float xs[16][DIM];
    __shared__ float y1s[16][HID];
    __shared__ float y2s[16][HID];

    int lane   = threadIdx.x & 63;
    int w      = threadIdx.x >> 6;
    int nb     = blockIdx.x * 16 + w * 4;   // first of this wave's 4 nodes

    // lanes 0-15: node t=0's 16 edges, lanes 16-31: t=1, ... (coalesced 256B)
    int myIdx = esrc[nb * DEG + lane];
    int myMsk = emask[nb * DEG + lane];

    float ax[4] = {0.f, 0.f, 0.f, 0.f};
    float ay[4] = {0.f, 0.f, 0.f, 0.f};

#pragma unroll
    for (int t = 0; t < 4; ++t) {
#pragma unroll
        for (int e = 0; e < DEG; ++e) {
            int s = __builtin_amdgcn_readlane(myIdx, t * 16 + e);  // SGPR
            int m = __builtin_amdgcn_readlane(myMsk, t * 16 + e);  // SGPR
            const __half* p = m ? inv16 : h16;                     // s_cselect
            __half2 hv = *(const __half2*)&p[(size_t)s * DIM + lane * 2];
            float2 v = __half22float2(hv);
            ax[t] += v.x; ay[t] += v.y;
        }
    }

    const float s16 = 0.0625f;  // mean over DEG=16, exact
#pragma unroll
    for (int t = 0; t < 4; ++t) {
        xs[w * 4 + t][lane * 2]     = ax[t] * s16;
        xs[w * 4 + t][lane * 2 + 1] = ay[t] * s16;
    }
    __syncthreads();

    float lo[4], hi[4];
    mlp_wave4(aw1, ab1, aw2, ab2, aw3, ab3,
              &xs[w * 4], &y1s[w * 4], &y2s[w * 4], lane, lo, hi);

#pragma unroll
    for (int t = 0; t < 4; ++t) {
        size_t row = (size_t)(dstBase + nb + t) * DIM;
        hout[row + lane]      = lo[t];
        hout[row + 64 + lane] = hi[t];
        h16[row + lane]       = __float2half(lo[t]);
        h16[row + 64 + lane]  = __float2half(hi[t]);
    }

    if (DO_INV) {
        __syncthreads();
#pragma unroll
        for (int t = 0; t < 4; ++t) {
            xs[w * 4 + t][lane]      = lo[t];
            xs[w * 4 + t][64 + lane] = hi[t];
        }
        __syncthreads();
        mlp_wave4(iw1, ib1, iw2, ib2, iw3, ib3,
                  &xs[w * 4], &y1s[w * 4], &y2s[w * 4], lane, lo, hi);
#pragma unroll
        for (int t = 0; t < 4; ++t) {
            size_t row = (size_t)(dstBase + nb + t) * DIM;
            inv16[row + lane]      = __float2half(lo[t]);
            inv16[row + 64 + lane] = __float2half(hi[t]);
        }
    }
}

// Level 0: convert h rows to fp16 mirror and compute inv mirror.
__global__ __launch_bounds__(256, 4) void inv0_kernel(
    const float* __restrict__ h0,
    __half* __restrict__ h16, __half* __restrict__ inv16,
    const float* __restrict__ iw1, const float* __restrict__ ib1,
    const float* __restrict__ iw2, const float* __restrict__ ib2,
    const float* __restrict__ iw3, const float* __restrict__ ib3)
{
    __shared__ float xs[16][DIM];
    __shared__ float y1s[16][HID];
    __shared__ float y2s[16][HID];

    int lane = threadIdx.x & 63;
    int w    = threadIdx.x >> 6;
    int nb   = blockIdx.x * 16 + w * 4;

#pragma unroll
    for (int t = 0; t < 4; ++t) {
        size_t row = (size_t)(nb + t) * DIM;
        float2 v = *(const float2*)&h0[row + lane * 2];
        xs[w * 4 + t][lane * 2]     = v.x;
        xs[w * 4 + t][lane * 2 + 1] = v.y;
        *(__half2*)&h16[row + lane * 2] = __float22half2_rn(v);
    }
    __syncthreads();

    float lo[4], hi[4];
    mlp_wave4(iw1, ib1, iw2, ib2, iw3, ib3,
              &xs[w * 4], &y1s[w * 4], &y2s[w * 4], lane, lo, hi);

#pragma unroll
    for (int t = 0; t < 4; ++t) {
        size_t row = (size_t)(nb + t) * DIM;
        inv16[row + lane]      = __float2half(lo[t]);
        inv16[row + 64 + lane] = __float2half(hi[t]);
    }
}

extern "C" void kernel_launch(void* const* d_in, const int* in_sizes, int n_in,
                              void* d_out, int out_size, void* d_ws, size_t ws_size,
                              hipStream_t stream)
{
    const float* h     = (const float*)d_in[0];
    const int*   esrc  = (const int*)d_in[1];   // [L-1][NPL][DEG]
    const int*   emask = (const int*)d_in[2];
    const float* iw1 = (const float*)d_in[3];
    const float* ib1 = (const float*)d_in[4];
    const float* iw2 = (const float*)d_in[5];
    const float* ib2 = (const float*)d_in[6];
    const float* iw3 = (const float*)d_in[7];
    const float* ib3 = (const float*)d_in[8];
    const float* aw1 = (const float*)d_in[9];
    const float* ab1 = (const float*)d_in[10];
    const float* aw2 = (const float*)d_in[11];
    const float* ab2 = (const float*)d_in[12];
    const float* aw3 = (const float*)d_in[13];
    const float* ab3 = (const float*)d_in[14];

    float*  hout  = (float*)d_out;
    __half* h16   = (__half*)d_ws;                     // [NN][DIM] fp16 mirror of h
    __half* inv16 = h16 + (size_t)NN * DIM;            // [7*NPL][DIM] fp16 inv mirror

    // level-0 fp32 rows pass through; levels 1..7 fully overwritten
    hipMemcpyAsync(hout, h, (size_t)NPL * DIM * sizeof(float),
                   hipMemcpyDeviceToDevice, stream);

    const int grid = NPL / 16;  // 1024 blocks, 4 blocks/CU

    inv0_kernel<<<grid, 256, 0, stream>>>(h, h16, inv16,
                                          iw1, ib1, iw2, ib2, iw3, ib3);

    for (int lvl = 1; lvl < LVLS; ++lvl) {
        const int* es = esrc  + (size_t)(lvl - 1) * NPL * DEG;
        const int* em = emask + (size_t)(lvl - 1) * NPL * DEG;
        if (lvl < LVLS - 1) {
            agg_kernel<true><<<grid, 256, 0, stream>>>(
                hout, h16, inv16, es, em,
                aw1, ab1, aw2, ab2, aw3, ab3,
                iw1, ib1, iw2, ib2, iw3, ib3, lvl * NPL);
        } else {
            agg_kernel<false><<<grid, 256, 0, stream>>>(
                hout, h16, inv16, es, em,
                aw1, ab1, aw2, ab2, aw3, ab3,
                iw1, ib1, iw2, ib2, iw3, ib3, lvl * NPL);
        }
    }
}

// Round 4
// 258.558 us; speedup vs baseline: 5.7032x; 2.3840x over previous
//
#include <hip/hip_runtime.h>
#include <hip/hip_fp16.h>

#define NN    131072
#define NPL   16384
#define LVLS  8
#define DEG   16
#define DIM   128
#define HID   64
#define BN    32              // dst nodes per block
#define NPW   8               // nodes gathered per wave (BN / 4 waves)
#define Y_LD  72              // padded leading dim for Y1/Y2 (halves)
#define PACK_HALVES 40960     // 2 MLPs * 4 waves * 10 frags * 512

typedef _Float16 f16x8 __attribute__((ext_vector_type(8)));
typedef float    f32x4 __attribute__((ext_vector_type(4)));

// half-index of x[row][col] in the 16B-chunk XOR-swizzled [32][128] fp16 tile.
// chunk (8 halves) c of row r lives at c ^ (r & 15): A-frag ds_read_b128 and
// the gather's half2 writes are both conflict-free.
__device__ __forceinline__ int xsw(int row, int col) {
    return row * DIM + (((col >> 3) ^ (row & 15)) << 3) + (col & 7);
}

// Per-wave persistent weight fragments for one MLP (B-operand layout of
// v_mfma_f32_16x16x32_f16: lane l holds col l&15, k-rows (l>>4)*8+j).
// Wave w owns output cols [w*16,w*16+16) of layers 1/2 and [w*32,w*32+32) of
// layer 3. ~40 VGPRs; loaded once per block (20 coalesced dwordx4 loads).
struct Frags {
    f16x8 w1[4];        // K=128: 4 k-tiles
    f16x8 w2[2];        // K=64:  2 k-tiles
    f16x8 w3[2][2];     // [n-tile][k-tile]
    float b1, b2, b3[2];
};

__device__ __forceinline__ void load_frags(const __half* __restrict__ pack,
    const float* __restrict__ b1, const float* __restrict__ b2,
    const float* __restrict__ b3, int p, int wv, int lane, Frags& F)
{
    const __half* base = pack + (size_t)((p * 4 + wv) * 10) * 512 + lane * 8;
#pragma unroll
    for (int f = 0; f < 4; ++f) F.w1[f] = *(const f16x8*)(base + f * 512);
#pragma unroll
    for (int f = 0; f < 2; ++f) F.w2[f] = *(const f16x8*)(base + (4 + f) * 512);
#pragma unroll
    for (int nt = 0; nt < 2; ++nt)
#pragma unroll
        for (int kt = 0; kt < 2; ++kt)
            F.w3[nt][kt] = *(const f16x8*)(base + (6 + nt * 2 + kt) * 512);
    int ll = lane & 15;
    F.b1    = b1[wv * 16 + ll];
    F.b2    = b2[wv * 16 + ll];
    F.b3[0] = b3[wv * 32 + ll];
    F.b3[1] = b3[wv * 32 + 16 + ll];
}

// 3-layer MLP via MFMA. xs: swizzled [BN][DIM] fp16 input (all waves read all
// of it). y1/y2: [BN][Y_LD] fp16 inter-layer buffers. Result: acc3[m][nt] =
// fp32 C/D tiles (row = m*16+(l>>4)*4+r, col = wv*32+nt*16+(l&15)).
// Contains the two inter-layer barriers; caller syncs before (xs ready) and
// after (before anyone re-reads/overwrites xs or y1).
__device__ __forceinline__ void mlp_mfma(const Frags& F,
    const __half* __restrict__ xs, __half* __restrict__ y1,
    __half* __restrict__ y2, int wv, int lane, f32x4 (&acc3)[2][2])
{
    int lg = lane >> 4, ll = lane & 15;
    // ---- layer 1: [32][128] @ [128][64]
#pragma unroll
    for (int m = 0; m < 2; ++m) {
        f32x4 acc = {F.b1, F.b1, F.b1, F.b1};
#pragma unroll
        for (int kt = 0; kt < 4; ++kt) {
            f16x8 a = *(const f16x8*)&xs[xsw(m * 16 + ll, kt * 32 + lg * 8)];
            acc = __builtin_amdgcn_mfma_f32_16x16x32_f16(a, F.w1[kt], acc, 0, 0, 0);
        }
#pragma unroll
        for (int r = 0; r < 4; ++r) {
            float v = acc[r];
            v = v >= 0.f ? v : 0.01f * v;
            y1[(m * 16 + lg * 4 + r) * Y_LD + wv * 16 + ll] = __float2half(v);
        }
    }
    __syncthreads();
    // ---- layer 2: [32][64] @ [64][64]
#pragma unroll
    for (int m = 0; m < 2; ++m) {
        f32x4 acc = {F.b2, F.b2, F.b2, F.b2};
#pragma unroll
        for (int kt = 0; kt < 2; ++kt) {
            f16x8 a = *(const f16x8*)&y1[(m * 16 + ll) * Y_LD + kt * 32 + lg * 8];
            acc = __builtin_amdgcn_mfma_f32_16x16x32_f16(a, F.w2[kt], acc, 0, 0, 0);
        }
#pragma unroll
        for (int r = 0; r < 4; ++r) {
            float v = acc[r];
            v = v >= 0.f ? v : 0.01f * v;
            y2[(m * 16 + lg * 4 + r) * Y_LD + wv * 16 + ll] = __float2half(v);
        }
    }
    __syncthreads();
    // ---- layer 3: [32][64] @ [64][128]
#pragma unroll
    for (int m = 0; m < 2; ++m) {
        f16x8 a0 = *(const f16x8*)&y2[(m * 16 + ll) * Y_LD + 0 * 32 + lg * 8];
        f16x8 a1 = *(const f16x8*)&y2[(m * 16 + ll) * Y_LD + 1 * 32 + lg * 8];
#pragma unroll
        for (int nt = 0; nt < 2; ++nt) {
            f32x4 acc = {F.b3[nt], F.b3[nt], F.b3[nt], F.b3[nt]};
            acc = __builtin_amdgcn_mfma_f32_16x16x32_f16(a0, F.w3[nt][0], acc, 0, 0, 0);
            acc = __builtin_amdgcn_mfma_f32_16x16x32_f16(a1, F.w3[nt][1], acc, 0, 0, 0);
            acc3[m][nt] = acc;
        }
    }
}

// Per-level fused kernel: gather fp16 (mask ? inv16 : h16) -> mean -> and-MLP
// -> hout fp32 (+ fp16 mirrors) -> (DO_INV) inv-MLP -> inv16 mirror.
template<bool DO_INV>
__global__ __launch_bounds__(256) void agg_kernel(
    float* __restrict__ hout,
    __half* __restrict__ h16, __half* __restrict__ inv16,
    const int* __restrict__ esrc, const int* __restrict__ emask,
    const __half* __restrict__ pack,
    const float* __restrict__ ab1, const float* __restrict__ ab2, const float* __restrict__ ab3,
    const float* __restrict__ ib1, const float* __restrict__ ib2, const float* __restrict__ ib3,
    int dstBase)
{
    __shared__ __half xs[BN * DIM];
    __shared__ __half y1[BN * Y_LD];
    __shared__ __half y2[BN * Y_LD];

    int lane = threadIdx.x & 63;
    int wv   = __builtin_amdgcn_readfirstlane((int)(threadIdx.x >> 6));
    int lg = lane >> 4, ll = lane & 15;
    int b0 = blockIdx.x * BN;

    Frags FA;
    load_frags(pack, ab1, ab2, ab3, 0, wv, lane, FA);
    Frags FI;
    if (DO_INV) load_frags(pack, ib1, ib2, ib3, 1, wv, lane, FI);

    // ---- gather: wave gathers NPW nodes; node uniform -> scalar idx/mask
#pragma unroll 2
    for (int n = 0; n < NPW; ++n) {
        int node = b0 + wv * NPW + n;            // level-local dst index
        const int* ep = esrc  + (size_t)node * DEG;
        const int* mp = emask + (size_t)node * DEG;
        float ax = 0.f, ay = 0.f;
#pragma unroll
        for (int e = 0; e < DEG; ++e) {
            int s = ep[e];
            int m = mp[e];
            const __half* p = m ? inv16 : h16;   // uniform s_cselect
            __half2 hv = *(const __half2*)&p[(size_t)s * DIM + lane * 2];
            float2 v = __half22float2(hv);
            ax += v.x; ay += v.y;
        }
        int lrow = wv * NPW + n;
        *(__half2*)&xs[xsw(lrow, lane * 2)] =
            __floats2half2_rn(ax * 0.0625f, ay * 0.0625f);
    }
    __syncthreads();

    // ---- and-MLP
    f32x4 acc[2][2];
    mlp_mfma(FA, xs, y1, y2, wv, lane, acc);

    // epilogue: hout fp32 from accumulators; xs <- fp16(new h) for inv input.
    // (xs reads finished before the L1->L2 barrier, safe to overwrite.)
#pragma unroll
    for (int m = 0; m < 2; ++m)
#pragma unroll
        for (int nt = 0; nt < 2; ++nt)
#pragma unroll
            for (int r = 0; r < 4; ++r) {
                int row = m * 16 + lg * 4 + r;
                int col = wv * 32 + nt * 16 + ll;
                float v = acc[m][nt][r];
                hout[(size_t)(dstBase + b0 + row) * DIM + col] = v;
                if (DO_INV) xs[xsw(row, col)] = __float2half(v);
            }

    if (DO_INV) {
        __syncthreads();
        // h16 mirror, coalesced half2 per lane
#pragma unroll
        for (int n = 0; n < NPW; ++n) {
            int lrow = wv * NPW + n;
            __half2 hv = *(const __half2*)&xs[xsw(lrow, lane * 2)];
            *(__half2*)&h16[(size_t)(dstBase + b0 + lrow) * DIM + lane * 2] = hv;
        }
        // ---- inv-MLP on the fresh h
        mlp_mfma(FI, xs, y1, y2, wv, lane, acc);
#pragma unroll
        for (int m = 0; m < 2; ++m)
#pragma unroll
            for (int nt = 0; nt < 2; ++nt)
#pragma unroll
                for (int r = 0; r < 4; ++r)
                    xs[xsw(m * 16 + lg * 4 + r, wv * 32 + nt * 16 + ll)] =
                        __float2half(acc[m][nt][r]);
        __syncthreads();
#pragma unroll
        for (int n = 0; n < NPW; ++n) {
            int lrow = wv * NPW + n;
            __half2 hv = *(const __half2*)&xs[xsw(lrow, lane * 2)];
            *(__half2*)&inv16[(size_t)(dstBase + b0 + lrow) * DIM + lane * 2] = hv;
        }
    }
}

// Level 0: h16 mirror + inv16 = inv_mlp(h0).
__global__ __launch_bounds__(256) void inv0_kernel(
    const float* __restrict__ h0,
    __half* __restrict__ h16, __half* __restrict__ inv16,
    const __half* __restrict__ pack,
    const float* __restrict__ ib1, const float* __restrict__ ib2,
    const float* __restrict__ ib3)
{
    __shared__ __half xs[BN * DIM];
    __shared__ __half y1[BN * Y_LD];
    __shared__ __half y2[BN * Y_LD];

    int lane = threadIdx.x & 63;
    int wv   = __builtin_amdgcn_readfirstlane((int)(threadIdx.x >> 6));
    int lg = lane >> 4, ll = lane & 15;
    int b0 = blockIdx.x * BN;

    Frags F;
    load_frags(pack, ib1, ib2, ib3, 1, wv, lane, F);

#pragma unroll
    for (int n = 0; n < NPW; ++n) {
        int lrow = wv * NPW + n;
        size_t row = (size_t)(b0 + lrow) * DIM;
        float2 v = *(const float2*)&h0[row + lane * 2];
        __half2 hv = __floats2half2_rn(v.x, v.y);
        *(__half2*)&xs[xsw(lrow, lane * 2)] = hv;
        *(__half2*)&h16[row + lane * 2] = hv;
    }
    __syncthreads();

    f32x4 acc[2][2];
    mlp_mfma(F, xs, y1, y2, wv, lane, acc);
#pragma unroll
    for (int m = 0; m < 2; ++m)
#pragma unroll
        for (int nt = 0; nt < 2; ++nt)
#pragma unroll
            for (int r = 0; r < 4; ++r)
                xs[xsw(m * 16 + lg * 4 + r, wv * 32 + nt * 16 + ll)] =
                    __float2half(acc[m][nt][r]);
    __syncthreads();
#pragma unroll
    for (int n = 0; n < NPW; ++n) {
        int lrow = wv * NPW + n;
        __half2 hv = *(const __half2*)&xs[xsw(lrow, lane * 2)];
        *(__half2*)&inv16[(size_t)(b0 + lrow) * DIM + lane * 2] = hv;
    }
}

// Pack all six weight matrices into per-wave per-frag per-lane fp16 order so
// kernels load fragments as single coalesced dwordx4s.
// pack[((p*4+w)*10+f)*512 + l*8 + j]; p=0:and p=1:inv.
__global__ void prep_kernel(const float* __restrict__ aw1, const float* __restrict__ aw2,
                            const float* __restrict__ aw3, const float* __restrict__ iw1,
                            const float* __restrict__ iw2, const float* __restrict__ iw3,
                            __half* __restrict__ pack)
{
    int t = blockIdx.x * blockDim.x + threadIdx.x;
    if (t >= PACK_HALVES) return;
    int p  = t / 20480;
    int r1 = t % 20480;
    int w  = r1 / 5120;
    int r2 = r1 % 5120;
    int f  = r2 / 512;
    int q  = r2 % 512;
    int l  = q >> 3;
    int j  = q & 7;
    int lg = l >> 4, ll = l & 15;

    const float* w1 = p ? iw1 : aw1;
    const float* w2 = p ? iw2 : aw2;
    const float* w3 = p ? iw3 : aw3;

    float val;
    if (f < 4)       val = w1[(f * 32 + lg * 8 + j) * HID + w * 16 + ll];
    else if (f < 6)  val = w2[((f - 4) * 32 + lg * 8 + j) * HID + w * 16 + ll];
    else {
        int nt = (f - 6) >> 1, kt = (f - 6) & 1;
        val = w3[(kt * 32 + lg * 8 + j) * DIM + w * 32 + nt * 16 + ll];
    }
    pack[t] = __float2half(val);
}

extern "C" void kernel_launch(void* const* d_in, const int* in_sizes, int n_in,
                              void* d_out, int out_size, void* d_ws, size_t ws_size,
                              hipStream_t stream)
{
    const float* h     = (const float*)d_in[0];
    const int*   esrc  = (const int*)d_in[1];   // [L-1][NPL][DEG]
    const int*   emask = (const int*)d_in[2];
    const float* iw1 = (const float*)d_in[3];
    const float* ib1 = (const float*)d_in[4];
    const float* iw2 = (const float*)d_in[5];
    const float* ib2 = (const float*)d_in[6];
    const float* iw3 = (const float*)d_in[7];
    const float* ib3 = (const float*)d_in[8];
    const float* aw1 = (const float*)d_in[9];
    const float* ab1 = (const float*)d_in[10];
    const float* aw2 = (const float*)d_in[11];
    const float* ab2 = (const float*)d_in[12];
    const float* aw3 = (const float*)d_in[13];
    const float* ab3 = (const float*)d_in[14];

    float*  hout  = (float*)d_out;
    __half* pack  = (__half*)d_ws;                        // 80 KB
    __half* h16   = pack + PACK_HALVES;                   // [NN][DIM] fp16
    __half* inv16 = h16 + (size_t)NN * DIM;               // [7*NPL][DIM] fp16

    prep_kernel<<<(PACK_HALVES + 255) / 256, 256, 0, stream>>>(
        aw1, aw2, aw3, iw1, iw2, iw3, pack);

    // level-0 fp32 rows pass through; levels 1..7 fully overwritten
    hipMemcpyAsync(hout, h, (size_t)NPL * DIM * sizeof(float),
                   hipMemcpyDeviceToDevice, stream);

    const int grid = NPL / BN;  // 512 blocks, 2 per CU

    inv0_kernel<<<grid, 256, 0, stream>>>(h, h16, inv16, pack, ib1, ib2, ib3);

    for (int lvl = 1; lvl < LVLS; ++lvl) {
        const int* es = esrc  + (size_t)(lvl - 1) * NPL * DEG;
        const int* em = emask + (size_t)(lvl - 1) * NPL * DEG;
        if (lvl < LVLS - 1)
            agg_kernel<true><<<grid, 256, 0, stream>>>(
                hout, h16, inv16, es, em, pack,
                ab1, ab2, ab3, ib1, ib2, ib3, lvl * NPL);
        else
            agg_kernel<false><<<grid, 256, 0, stream>>>(
                hout, h16, inv16, es, em, pack,
                ab1, ab2, ab3, ib1, ib2, ib3, lvl * NPL);
    }
}

// Round 6
// 243.047 us; speedup vs baseline: 6.0672x; 1.0638x over previous
//
#include <hip/hip_runtime.h>
#include <hip/hip_fp16.h>

#define NN    131072
#define NPL   16384
#define LVLS  8
#define DEG   16
#define DIM   128
#define HID   64
#define BN    16              // dst nodes per block
#define NPW   4               // nodes gathered per wave (BN / 4 waves)
#define Y_LD  72              // padded leading dim for Y1/Y2 (halves)
#define PACK_HALVES 40960     // 2 MLPs * 4 waves * 10 frags * 512

typedef _Float16 f16x8 __attribute__((ext_vector_type(8)));
typedef float    f32x4 __attribute__((ext_vector_type(4)));

// half-index of x[row][col] in the 16B-chunk XOR-swizzled [16][128] fp16 tile.
// chunk (8 halves) c of row r lives at c ^ (r & 15): A-frag ds_read_b128 and
// the gather's half2 writes are both conflict-free (proven round 4).
__device__ __forceinline__ int xsw(int row, int col) {
    return row * DIM + (((col >> 3) ^ (row & 15)) << 3) + (col & 7);
}

// Per-wave persistent weight fragments for one MLP (B-operand layout of
// v_mfma_f32_16x16x32_f16). Wave w owns output cols [w*16,w*16+16) of layers
// 1/2 and [w*32,w*32+32) of layer 3. 40 VGPRs; 10 coalesced dwordx4 loads.
struct Frags {
    f16x8 w1[4];        // K=128: 4 k-tiles
    f16x8 w2[2];        // K=64:  2 k-tiles
    f16x8 w3[2][2];     // [n-tile][k-tile]
    float b1, b2, b3[2];
};

__device__ __forceinline__ void load_frags(const __half* __restrict__ pack,
    const float* __restrict__ b1, const float* __restrict__ b2,
    const float* __restrict__ b3, int p, int wv, int lane, Frags& F)
{
    const __half* base = pack + (size_t)((p * 4 + wv) * 10) * 512 + lane * 8;
#pragma unroll
    for (int f = 0; f < 4; ++f) F.w1[f] = *(const f16x8*)(base + f * 512);
#pragma unroll
    for (int f = 0; f < 2; ++f) F.w2[f] = *(const f16x8*)(base + (4 + f) * 512);
#pragma unroll
    for (int nt = 0; nt < 2; ++nt)
#pragma unroll
        for (int kt = 0; kt < 2; ++kt)
            F.w3[nt][kt] = *(const f16x8*)(base + (6 + nt * 2 + kt) * 512);
    int ll = lane & 15;
    F.b1    = b1[wv * 16 + ll];
    F.b2    = b2[wv * 16 + ll];
    F.b3[0] = b3[wv * 32 + ll];
    F.b3[1] = b3[wv * 32 + 16 + ll];
}

// 3-layer MLP via MFMA, M = 16 rows (one tile). Result acc3[nt]: fp32 C/D,
// row = (lane>>4)*4 + r, col = wv*32 + nt*16 + (lane&15).
// Two internal barriers; caller syncs before (xs ready) and after.
__device__ __forceinline__ void mlp_mfma(const Frags& F,
    const __half* __restrict__ xs, __half* __restrict__ y1,
    __half* __restrict__ y2, int wv, int lane, f32x4 (&acc3)[2])
{
    int lg = lane >> 4, ll = lane & 15;
    // ---- layer 1: [16][128] @ [128][64]
    f32x4 acc = {F.b1, F.b1, F.b1, F.b1};
#pragma unroll
    for (int kt = 0; kt < 4; ++kt) {
        f16x8 a = *(const f16x8*)&xs[xsw(ll, kt * 32 + lg * 8)];
        acc = __builtin_amdgcn_mfma_f32_16x16x32_f16(a, F.w1[kt], acc, 0, 0, 0);
    }
#pragma unroll
    for (int r = 0; r < 4; ++r) {
        float v = acc[r];
        v = v >= 0.f ? v : 0.01f * v;
        y1[(lg * 4 + r) * Y_LD + wv * 16 + ll] = __float2half(v);
    }
    __syncthreads();
    // ---- layer 2: [16][64] @ [64][64]
    acc = f32x4{F.b2, F.b2, F.b2, F.b2};
#pragma unroll
    for (int kt = 0; kt < 2; ++kt) {
        f16x8 a = *(const f16x8*)&y1[ll * Y_LD + kt * 32 + lg * 8];
        acc = __builtin_amdgcn_mfma_f32_16x16x32_f16(a, F.w2[kt], acc, 0, 0, 0);
    }
#pragma unroll
    for (int r = 0; r < 4; ++r) {
        float v = acc[r];
        v = v >= 0.f ? v : 0.01f * v;
        y2[(lg * 4 + r) * Y_LD + wv * 16 + ll] = __float2half(v);
    }
    __syncthreads();
    // ---- layer 3: [16][64] @ [64][128]
    f16x8 a0 = *(const f16x8*)&y2[ll * Y_LD + 0 * 32 + lg * 8];
    f16x8 a1 = *(const f16x8*)&y2[ll * Y_LD + 1 * 32 + lg * 8];
#pragma unroll
    for (int nt = 0; nt < 2; ++nt) {
        f32x4 c = {F.b3[nt], F.b3[nt], F.b3[nt], F.b3[nt]};
        c = __builtin_amdgcn_mfma_f32_16x16x32_f16(a0, F.w3[nt][0], c, 0, 0, 0);
        c = __builtin_amdgcn_mfma_f32_16x16x32_f16(a1, F.w3[nt][1], c, 0, 0, 0);
        acc3[nt] = c;
    }
}

// acc3 -> swizzled fp16 xs tile (xs last read 2 barriers ago: safe).
__device__ __forceinline__ void acc_to_xs(const f32x4 (&acc3)[2],
    __half* __restrict__ xs, int wv, int lane)
{
    int lg = lane >> 4, ll = lane & 15;
#pragma unroll
    for (int nt = 0; nt < 2; ++nt)
#pragma unroll
        for (int r = 0; r < 4; ++r)
            xs[xsw(lg * 4 + r, wv * 32 + nt * 16 + ll)] = __float2half(acc3[nt][r]);
}

// Per-level fused kernel: gather fp16 (mask ? inv16 : h16) -> mean -> and-MLP
// -> hout (+ mirrors); (DO_INV) inv-MLP -> inv16. Block = 256 / 16 nodes,
// grid = 1024 -> 4 blocks/CU.
template<bool DO_INV>
__global__ __launch_bounds__(256, 4) void agg_kernel(
    float* __restrict__ hout,
    __half* __restrict__ h16, __half* __restrict__ inv16,
    const int* __restrict__ esrc, const int* __restrict__ emask,
    const __half* __restrict__ pack,
    const float* __restrict__ ab1, const float* __restrict__ ab2, const float* __restrict__ ab3,
    const float* __restrict__ ib1, const float* __restrict__ ib2, const float* __restrict__ ib3,
    int dstBase)
{
    __shared__ __half xs[BN * DIM];
    __shared__ __half y1[BN * Y_LD];
    __shared__ __half y2[BN * Y_LD];

    int lane = threadIdx.x & 63;
    int wv   = __builtin_amdgcn_readfirstlane((int)(threadIdx.x >> 6));
    int b0   = blockIdx.x * BN;

    Frags FA;
    load_frags(pack, ab1, ab2, ab3, 0, wv, lane, FA);

    // ---- gather: wave gathers NPW nodes; node uniform -> scalar idx/mask
#pragma unroll 2
    for (int n = 0; n < NPW; ++n) {
        int node = b0 + wv * NPW + n;            // level-local dst index
        const int* ep = esrc  + (size_t)node * DEG;
        const int* mp = emask + (size_t)node * DEG;
        float ax = 0.f, ay = 0.f;
#pragma unroll
        for (int e = 0; e < DEG; ++e) {
            int s = ep[e];
            int m = mp[e];
            const __half* p = m ? inv16 : h16;   // uniform s_cselect
            __half2 hv = *(const __half2*)&p[(size_t)s * DIM + lane * 2];
            float2 v = __half22float2(hv);
            ax += v.x; ay += v.y;
        }
        *(__half2*)&xs[xsw(wv * NPW + n, lane * 2)] =
            __floats2half2_rn(ax * 0.0625f, ay * 0.0625f);
    }
    __syncthreads();

    // ---- and-MLP
    f32x4 acc[2];
    mlp_mfma(FA, xs, y1, y2, wv, lane, acc);
    acc_to_xs(acc, xs, wv, lane);
    __syncthreads();

    // ---- hout (fp32 from fp16 tile, coalesced) + h16 mirror
#pragma unroll
    for (int n = 0; n < NPW; ++n) {
        int lrow = wv * NPW + n;
        size_t row = (size_t)(dstBase + b0 + lrow) * DIM;
        __half2 hv = *(const __half2*)&xs[xsw(lrow, lane * 2)];
        *(float2*)&hout[row + lane * 2] = __half22float2(hv);
        if (DO_INV) *(__half2*)&h16[row + lane * 2] = hv;  // last level: never read
    }

    if (DO_INV) {
        // ---- inv-MLP on the fresh h (frags loaded lazily to cap VGPRs)
        Frags FI;
        load_frags(pack, ib1, ib2, ib3, 1, wv, lane, FI);
        mlp_mfma(FI, xs, y1, y2, wv, lane, acc);
        acc_to_xs(acc, xs, wv, lane);
        __syncthreads();
#pragma unroll
        for (int n = 0; n < NPW; ++n) {
            int lrow = wv * NPW + n;
            __half2 hv = *(const __half2*)&xs[xsw(lrow, lane * 2)];
            *(__half2*)&inv16[(size_t)(dstBase + b0 + lrow) * DIM + lane * 2] = hv;
        }
    }
}

// Level 0: hout passthrough (exact fp32) + h16 mirror + inv16 = inv_mlp(h0).
__global__ __launch_bounds__(256, 4) void inv0_kernel(
    const float* __restrict__ h0, float* __restrict__ hout,
    __half* __restrict__ h16, __half* __restrict__ inv16,
    const __half* __restrict__ pack,
    const float* __restrict__ ib1, const float* __restrict__ ib2,
    const float* __restrict__ ib3)
{
    __shared__ __half xs[BN * DIM];
    __shared__ __half y1[BN * Y_LD];
    __shared__ __half y2[BN * Y_LD];

    int lane = threadIdx.x & 63;
    int wv   = __builtin_amdgcn_readfirstlane((int)(threadIdx.x >> 6));
    int b0   = blockIdx.x * BN;

    Frags F;
    load_frags(pack, ib1, ib2, ib3, 1, wv, lane, F);

#pragma unroll
    for (int n = 0; n < NPW; ++n) {
        int lrow = wv * NPW + n;
        size_t row = (size_t)(b0 + lrow) * DIM;
        float2 v = *(const float2*)&h0[row + lane * 2];
        __half2 hv = __floats2half2_rn(v.x, v.y);
        *(float2*)&hout[row + lane * 2] = v;       // exact passthrough
        *(__half2*)&h16[row + lane * 2] = hv;
        *(__half2*)&xs[xsw(lrow, lane * 2)] = hv;
    }
    __syncthreads();

    f32x4 acc[2];
    mlp_mfma(F, xs, y1, y2, wv, lane, acc);
    acc_to_xs(acc, xs, wv, lane);
    __syncthreads();
#pragma unroll
    for (int n = 0; n < NPW; ++n) {
        int lrow = wv * NPW + n;
        __half2 hv = *(const __half2*)&xs[xsw(lrow, lane * 2)];
        *(__half2*)&inv16[(size_t)(b0 + lrow) * DIM + lane * 2] = hv;
    }
}

// Pack the six weight matrices into per-wave per-frag per-lane fp16 order.
// pack[((p*4+w)*10+f)*512 + l*8 + j]; p=0:and p=1:inv.
__global__ void prep_kernel(const float* __restrict__ aw1, const float* __restrict__ aw2,
                            const float* __restrict__ aw3, const float* __restrict__ iw1,
                            const float* __restrict__ iw2, const float* __restrict__ iw3,
                            __half* __restrict__ pack)
{
    int t = blockIdx.x * blockDim.x + threadIdx.x;
    if (t >= PACK_HALVES) return;
    int p  = t / 20480;
    int r1 = t % 20480;
    int w  = r1 / 5120;
    int r2 = r1 % 5120;
    int f  = r2 / 512;
    int q  = r2 % 512;
    int l  = q >> 3;
    int j  = q & 7;
    int lg = l >> 4, ll = l & 15;

    const float* w1 = p ? iw1 : aw1;
    const float* w2 = p ? iw2 : aw2;
    const float* w3 = p ? iw3 : aw3;

    float val;
    if (f < 4)       val = w1[(f * 32 + lg * 8 + j) * HID + w * 16 + ll];
    else if (f < 6)  val = w2[((f - 4) * 32 + lg * 8 + j) * HID + w * 16 + ll];
    else {
        int nt = (f - 6) >> 1, kt = (f - 6) & 1;
        val = w3[(kt * 32 + lg * 8 + j) * DIM + w * 32 + nt * 16 + ll];
    }
    pack[t] = __float2half(val);
}

extern "C" void kernel_launch(void* const* d_in, const int* in_sizes, int n_in,
                              void* d_out, int out_size, void* d_ws, size_t ws_size,
                              hipStream_t stream)
{
    const float* h     = (const float*)d_in[0];
    const int*   esrc  = (const int*)d_in[1];   // [L-1][NPL][DEG]
    const int*   emask = (const int*)d_in[2];
    const float* iw1 = (const float*)d_in[3];
    const float* ib1 = (const float*)d_in[4];
    const float* iw2 = (const float*)d_in[5];
    const float* ib2 = (const float*)d_in[6];
    const float* iw3 = (const float*)d_in[7];
    const float* ib3 = (const float*)d_in[8];
    const float* aw1 = (const float*)d_in[9];
    const float* ab1 = (const float*)d_in[10];
    const float* aw2 = (const float*)d_in[11];
    const float* ab2 = (const float*)d_in[12];
    const float* aw3 = (const float*)d_in[13];
    const float* ab3 = (const float*)d_in[14];

    float*  hout  = (float*)d_out;
    __half* pack  = (__half*)d_ws;                        // 80 KB
    __half* h16   = pack + PACK_HALVES;                   // [NN][DIM] fp16
    __half* inv16 = h16 + (size_t)NN * DIM;               // [7*NPL][DIM] fp16

    prep_kernel<<<(PACK_HALVES + 255) / 256, 256, 0, stream>>>(
        aw1, aw2, aw3, iw1, iw2, iw3, pack);

    const int grid = NPL / BN;  // 1024 blocks -> 4 per CU

    inv0_kernel<<<grid, 256, 0, stream>>>(h, hout, h16, inv16, pack,
                                          ib1, ib2, ib3);

    for (int lvl = 1; lvl < LVLS; ++lvl) {
        const int* es = esrc  + (size_t)(lvl - 1) * NPL * DEG;
        const int* em = emask + (size_t)(lvl - 1) * NPL * DEG;
        if (lvl < LVLS - 1)
            agg_kernel<true><<<grid, 256, 0, stream>>>(
                hout, h16, inv16, es, em, pack,
                ab1, ab2, ab3, ib1, ib2, ib3, lvl * NPL);
        else
            agg_kernel<false><<<grid, 256, 0, stream>>>(
                hout, h16, inv16, es, em, pack,
                ab1, ab2, ab3, ib1, ib2, ib3, lvl * NPL);
    }
}